// Round 1
// baseline (326.559 us; speedup 1.0000x reference)
//
#include <hip/hip_runtime.h>

#define T_STEPS 60
#define HID 128
#define ROWS 64

typedef __attribute__((ext_vector_type(8))) short short8;
typedef __attribute__((ext_vector_type(4))) float f32x4;

__device__ __forceinline__ unsigned short f2bf(float f) {
  unsigned u = __float_as_uint(f);
  return (unsigned short)((u + 0x7fffu + ((u >> 16) & 1u)) >> 16);
}
__device__ __forceinline__ float bf2f(short s) {
  return __uint_as_float(((unsigned)(unsigned short)s) << 16);
}
__device__ __forceinline__ float sigm(float x) {
  return __builtin_amdgcn_rcpf(1.0f + __expf(-x));
}
__device__ __forceinline__ float tanh_f(float x) {
  return fmaf(2.0f, __builtin_amdgcn_rcpf(1.0f + __expf(-2.0f * x)), -1.0f);
}

__global__ __launch_bounds__(512, 2) void lstm_fused(
    const float* __restrict__ x, const float* __restrict__ W_enc,
    const float* __restrict__ b_enc, const float* __restrict__ W_ih,
    const float* __restrict__ W_hh, const float* __restrict__ b_ih,
    const float* __restrict__ b_hh, const float* __restrict__ W_dec,
    const float* __restrict__ b_dec, float* __restrict__ out) {
  __shared__ __align__(16) unsigned short h_lds[ROWS * HID];

  const int tid = threadIdx.x;
  const int wav = tid >> 6;
  const int lane = tid & 63;
  const int l15 = lane & 15;
  const int l4 = lane >> 4;
  const int u = wav * 16 + l15;        // hidden unit owned by this lane
  const int row0 = blockIdx.x * ROWS;  // global batch row base

  // zero h_lds (h_0 = 0)
  {
    short8 z = {};
    short8* p = (short8*)h_lds;
    for (int i = tid; i < ROWS * HID / 8; i += 512) p[i] = z;
  }

  // ---- precompute xp = enc @ W_ih^T + b_ih + b_hh, in accumulator layout ----
  float xr[16][3];
#pragma unroll
  for (int rt = 0; rt < 4; ++rt)
#pragma unroll
    for (int v = 0; v < 4; ++v) {
      int r = rt * 16 + 4 * l4 + v;
      const float* xp_ = x + (size_t)(row0 + r) * 3;
      xr[rt * 4 + v][0] = xp_[0];
      xr[rt * 4 + v][1] = xp_[1];
      xr[rt * 4 + v][2] = xp_[2];
    }
  float xpv[4][16];
#pragma unroll
  for (int gt = 0; gt < 4; ++gt) {
    float bias = b_ih[gt * 128 + u] + b_hh[gt * 128 + u];
#pragma unroll
    for (int j = 0; j < 16; ++j) xpv[gt][j] = bias;
  }
  for (int e = 0; e < 64; ++e) {
    float we0 = W_enc[e * 3 + 0], we1 = W_enc[e * 3 + 1], we2 = W_enc[e * 3 + 2];
    float be = b_enc[e];
    float wv[4];
#pragma unroll
    for (int gt = 0; gt < 4; ++gt) wv[gt] = W_ih[(size_t)(gt * 128 + u) * 64 + e];
#pragma unroll
    for (int j = 0; j < 16; ++j) {
      float ev = fmaf(we0, xr[j][0], fmaf(we1, xr[j][1], fmaf(we2, xr[j][2], be)));
#pragma unroll
      for (int gt = 0; gt < 4; ++gt) xpv[gt][j] = fmaf(wv[gt], ev, xpv[gt][j]);
    }
  }

  // ---- W_hh as register-resident bf16 B-fragments ----
  // B-frag (16x16x32): lane holds B[k = kt*32 + 8*l4 + j][col = gc + l15]
  //                  = W_hh[gc + l15][kt*32 + 8*l4 + j]  (contiguous in k)
  short8 bw[4][4];
#pragma unroll
  for (int gt = 0; gt < 4; ++gt)
#pragma unroll
    for (int kt = 0; kt < 4; ++kt) {
      const float* p = W_hh + (size_t)(gt * 128 + u) * HID + kt * 32 + 8 * l4;
      short8 f;
#pragma unroll
      for (int j = 0; j < 8; ++j) f[j] = (short)f2bf(p[j]);
      bw[gt][kt] = f;
    }

  float c_st[16];
#pragma unroll
  for (int j = 0; j < 16; ++j) c_st[j] = 0.0f;

  const float bdec = b_dec[0];
  const int dr = wav * 8 + (lane & 7);  // decode: row handled by this lane
  const int ug = lane >> 3;             // decode: unit group (16 units)

  __syncthreads();

  for (int t = 0; t < T_STEPS; ++t) {
    // ---- gates = xp + h @ W_hh^T (MFMA) ----
    f32x4 acc[4][4];
#pragma unroll
    for (int gt = 0; gt < 4; ++gt)
#pragma unroll
      for (int rt = 0; rt < 4; ++rt) {
        f32x4 a;
        a[0] = xpv[gt][rt * 4 + 0];
        a[1] = xpv[gt][rt * 4 + 1];
        a[2] = xpv[gt][rt * 4 + 2];
        a[3] = xpv[gt][rt * 4 + 3];
        acc[gt][rt] = a;
      }
#pragma unroll
    for (int rt = 0; rt < 4; ++rt) {
#pragma unroll
      for (int kt = 0; kt < 4; ++kt) {
        int r = rt * 16 + l15;
        unsigned byte = (unsigned)((r * HID + kt * 32 + 8 * l4) * 2) ^ ((unsigned)(r & 7) << 4);
        short8 af = *(const short8*)((const char*)h_lds + byte);
#pragma unroll
        for (int gt = 0; gt < 4; ++gt)
          acc[gt][rt] = __builtin_amdgcn_mfma_f32_16x16x32_bf16(af, bw[gt][kt], acc[gt][rt], 0, 0, 0);
      }
    }
    // ---- gate activations + state update (all in-register; lane owns unit u) ----
    unsigned short hb[16];
#pragma unroll
    for (int rt = 0; rt < 4; ++rt)
#pragma unroll
      for (int v = 0; v < 4; ++v) {
        int j = rt * 4 + v;
        float ig = sigm(acc[0][rt][v]);
        float fg = sigm(acc[1][rt][v]);
        float gg = tanh_f(acc[2][rt][v]);
        float og = sigm(acc[3][rt][v]);
        float c = fmaf(fg, c_st[j], ig * gg);
        c_st[j] = c;
        float h = og * tanh_f(c);
        hb[j] = f2bf(h);
      }
    __syncthreads();  // all reads of h_{t-1} complete
#pragma unroll
    for (int rt = 0; rt < 4; ++rt)
#pragma unroll
      for (int v = 0; v < 4; ++v) {
        int r = rt * 16 + 4 * l4 + v;
        unsigned byte = (unsigned)((r * HID + u) * 2) ^ ((unsigned)(r & 7) << 4);
        *(unsigned short*)((char*)h_lds + byte) = hb[rt * 4 + v];
      }
    __syncthreads();  // h_t complete in LDS
    // ---- fused decode: y[r,t] = sigmoid(W_dec . h_t[r] + b_dec) ----
    {
      unsigned pre = (unsigned)((dr * HID + ug * 16) * 2);
      unsigned swz = (unsigned)(dr & 7) << 4;
      short8 h0 = *(const short8*)((const char*)h_lds + (pre ^ swz));
      short8 h1 = *(const short8*)((const char*)h_lds + ((pre + 16) ^ swz));
      const float* wd = W_dec + ug * 16;
      float dot = 0.0f;
#pragma unroll
      for (int i = 0; i < 8; ++i) dot = fmaf(bf2f(h0[i]), wd[i], dot);
#pragma unroll
      for (int i = 0; i < 8; ++i) dot = fmaf(bf2f(h1[i]), wd[8 + i], dot);
      dot += __shfl_xor(dot, 8, 64);
      dot += __shfl_xor(dot, 16, 64);
      dot += __shfl_xor(dot, 32, 64);
      if (ug == 0) out[(size_t)(row0 + dr) * T_STEPS + t] = sigm(dot + bdec);
    }
  }
}

extern "C" void kernel_launch(void* const* d_in, const int* in_sizes, int n_in,
                              void* d_out, int out_size, void* d_ws, size_t ws_size,
                              hipStream_t stream) {
  const float* x = (const float*)d_in[0];
  const float* W_enc = (const float*)d_in[1];
  const float* b_enc = (const float*)d_in[2];
  const float* W_ih = (const float*)d_in[3];
  const float* W_hh = (const float*)d_in[4];
  const float* b_ih = (const float*)d_in[5];
  const float* b_hh = (const float*)d_in[6];
  const float* W_dec = (const float*)d_in[7];
  const float* b_dec = (const float*)d_in[8];
  float* out = (float*)d_out;

  dim3 grid(16384 / ROWS);  // 256 blocks, 64 rows each
  dim3 block(512);
  lstm_fused<<<grid, block, 0, stream>>>(x, W_enc, b_enc, W_ih, W_hh, b_ih, b_hh,
                                         W_dec, b_dec, out);
}

// Round 6
// 261.239 us; speedup vs baseline: 1.2500x; 1.2500x over previous
//
#include <hip/hip_runtime.h>

#define T_STEPS 60
#define HID 128
#define ROWS 16
#define NBLK (16384 / ROWS)  // 1024 blocks

typedef __attribute__((ext_vector_type(8))) short short8;
typedef __attribute__((ext_vector_type(4))) short short4v;
typedef __attribute__((ext_vector_type(4))) float f32x4;

__device__ __forceinline__ unsigned short f2bf(float f) {
  unsigned u = __float_as_uint(f);
  return (unsigned short)((u + 0x7fffu + ((u >> 16) & 1u)) >> 16);
}
__device__ __forceinline__ float bf2f(unsigned short s) {
  return __uint_as_float(((unsigned)s) << 16);
}
__device__ __forceinline__ float sigm(float x) {
  return __builtin_amdgcn_rcpf(1.0f + __expf(-x));
}
__device__ __forceinline__ float tanh_f(float x) {
  return fmaf(2.0f, __builtin_amdgcn_rcpf(1.0f + __expf(-2.0f * x)), -1.0f);
}

// LDS map (bytes):
//   [0,4096):     h buffer 0 (16 rows x 128 units bf16, row r at r*256, swizzled)
//   [4096,8192):  h buffer 1
//   [8192,8704):  W_dec f32 copy
#define HB0 0
#define HB1 4096
#define WD_BASE 8192
#define LDS_BYTES 8704

__global__ __launch_bounds__(512, 4) void lstm_fused(
    const float* __restrict__ x, const float* __restrict__ W_enc,
    const float* __restrict__ b_enc, const float* __restrict__ W_ih,
    const float* __restrict__ W_hh, const float* __restrict__ b_ih,
    const float* __restrict__ b_hh, const float* __restrict__ W_dec,
    const float* __restrict__ b_dec, float* __restrict__ out) {
  __shared__ __align__(16) unsigned char lds[LDS_BYTES];

  const int tid = threadIdx.x;
  const int wav = tid >> 6;
  const int lane = tid & 63;
  const int l15 = lane & 15;
  const int l4 = lane >> 4;
  const int u = wav * 16 + l15;        // hidden unit owned by this lane
  const int row0 = blockIdx.x * ROWS;  // global batch row base

  // zero h buf0 (4096 B)
  for (int i = tid; i < 1024; i += 512) ((unsigned*)(lds + HB0))[i] = 0u;
  // copy W_dec into LDS
  if (tid < 128) ((float*)(lds + WD_BASE))[tid] = W_dec[tid];

  // ---- xp = enc @ W_ih^T + b_ih + b_hh, f32 IN REGISTERS, acc layout ----
  // (f16/LDS xp was the R3/R5 failure: coherent per-step bias amplified by
  //  the recurrence. Must stay f32.)
  float xpv[4][4];
  {
    float xr0[4], xr1[4], xr2[4];
#pragma unroll
    for (int v = 0; v < 4; ++v) {
      int r = 4 * l4 + v;  // C-fragment row for this lane
      const float* xp_ = x + (size_t)(row0 + r) * 3;
      xr0[v] = xp_[0];
      xr1[v] = xp_[1];
      xr2[v] = xp_[2];
    }
#pragma unroll
    for (int gt = 0; gt < 4; ++gt) {
      float bias = b_ih[gt * 128 + u] + b_hh[gt * 128 + u];
#pragma unroll
      for (int v = 0; v < 4; ++v) xpv[gt][v] = bias;
    }
    for (int e = 0; e < 64; ++e) {
      float we0 = W_enc[e * 3], we1 = W_enc[e * 3 + 1], we2 = W_enc[e * 3 + 2];
      float be = b_enc[e];
      float wv0 = W_ih[(size_t)u * 64 + e];
      float wv1 = W_ih[(size_t)(128 + u) * 64 + e];
      float wv2 = W_ih[(size_t)(256 + u) * 64 + e];
      float wv3 = W_ih[(size_t)(384 + u) * 64 + e];
#pragma unroll
      for (int v = 0; v < 4; ++v) {
        float ev = fmaf(we0, xr0[v], fmaf(we1, xr1[v], fmaf(we2, xr2[v], be)));
        xpv[0][v] = fmaf(wv0, ev, xpv[0][v]);
        xpv[1][v] = fmaf(wv1, ev, xpv[1][v]);
        xpv[2][v] = fmaf(wv2, ev, xpv[2][v]);
        xpv[3][v] = fmaf(wv3, ev, xpv[3][v]);
      }
    }
  }

  // ---- W_hh as register-resident bf16 B-fragments (layout verified in R1) ----
  short8 bw[4][4];
#pragma unroll
  for (int gt = 0; gt < 4; ++gt)
#pragma unroll
    for (int kt = 0; kt < 4; ++kt) {
      const float* p = W_hh + (size_t)(gt * 128 + u) * HID + kt * 32 + 8 * l4;
      short8 f;
#pragma unroll
      for (int j = 0; j < 8; ++j) f[j] = (short)f2bf(p[j]);
      bw[gt][kt] = f;
    }

  float c_st[4];
#pragma unroll
  for (int v = 0; v < 4; ++v) c_st[v] = 0.0f;

  // ---- precomputed LDS addresses (swizzle bits 4-6, consistent on rd/wr) ----
  const unsigned swzA =
      (((unsigned)(l15 & 7)) << 4) ^ (((unsigned)(l15 & 8)) << 2);
  unsigned rdA[4];
#pragma unroll
  for (int kt = 0; kt < 4; ++kt)
    rdA[kt] = ((unsigned)(l15 * 256 + l4 * 16 + kt * 64)) ^ swzA;
  unsigned wrA[4];
#pragma unroll
  for (int v = 0; v < 4; ++v) {
    unsigned rr = (unsigned)(4 * l4 + v);
    wrA[v] = (rr * 256 + (unsigned)u * 2) ^ ((rr & 7u) << 4) ^ ((rr & 8u) << 2);
  }
  // decode: half-wave handles one row; 32 lanes x 4 units each
  const int drow = wav * 2 + (l4 >> 1);
  const int idx = (l4 & 1) * 16 + l15;  // unit group: units idx*4 .. idx*4+3
  const unsigned dA = ((unsigned)(drow * 256 + idx * 8)) ^
                      (((unsigned)(drow & 7)) << 4) ^ (((unsigned)(drow & 8)) << 2);
  const int outIdx = (row0 + drow) * T_STEPS;
  const float bdec = b_dec[0];

  __syncthreads();

#define STEP(RB, WB, tcur)                                                     \
  {                                                                            \
    f32x4 acc[4];                                                              \
    _Pragma("unroll") for (int gt = 0; gt < 4; ++gt) {                         \
      acc[gt][0] = xpv[gt][0];                                                 \
      acc[gt][1] = xpv[gt][1];                                                 \
      acc[gt][2] = xpv[gt][2];                                                 \
      acc[gt][3] = xpv[gt][3];                                                 \
    }                                                                          \
    _Pragma("unroll") for (int kt = 0; kt < 4; ++kt) {                         \
      short8 af = *(const short8*)(lds + (RB) + rdA[kt]);                      \
      _Pragma("unroll") for (int gt = 0; gt < 4; ++gt) acc[gt] =               \
          __builtin_amdgcn_mfma_f32_16x16x32_bf16(af, bw[gt][kt], acc[gt],     \
                                                  0, 0, 0);                    \
    }                                                                          \
    _Pragma("unroll") for (int v = 0; v < 4; ++v) {                            \
      float ig = sigm(acc[0][v]);                                              \
      float fg = sigm(acc[1][v]);                                              \
      float gg = tanh_f(acc[2][v]);                                            \
      float og = sigm(acc[3][v]);                                              \
      float c = fmaf(fg, c_st[v], ig * gg);                                    \
      c_st[v] = c;                                                             \
      *(unsigned short*)(lds + (WB) + wrA[v]) = f2bf(og * tanh_f(c));          \
    }                                                                          \
    __syncthreads();                                                           \
    {                                                                          \
      short4v hv = *(const short4v*)(lds + (WB) + dA);                         \
      f32x4 wd = *(const f32x4*)(lds + WD_BASE + idx * 16);                    \
      float dot = 0.f;                                                         \
      _Pragma("unroll") for (int i = 0; i < 4; ++i) dot =                      \
          fmaf(bf2f((unsigned short)hv[i]), wd[i], dot);                       \
      dot += __shfl_xor(dot, 1, 64);                                           \
      dot += __shfl_xor(dot, 2, 64);                                           \
      dot += __shfl_xor(dot, 4, 64);                                           \
      dot += __shfl_xor(dot, 8, 64);                                           \
      dot += __shfl_xor(dot, 16, 64);                                          \
      if ((lane & 31) == 0) out[outIdx + (tcur)] = sigm(dot + bdec);           \
    }                                                                          \
  }

  for (int t = 0; t < T_STEPS; t += 2) {
    STEP(HB0, HB1, t)
    STEP(HB1, HB0, t + 1)
  }
#undef STEP
}

extern "C" void kernel_launch(void* const* d_in, const int* in_sizes, int n_in,
                              void* d_out, int out_size, void* d_ws, size_t ws_size,
                              hipStream_t stream) {
  const float* x = (const float*)d_in[0];
  const float* W_enc = (const float*)d_in[1];
  const float* b_enc = (const float*)d_in[2];
  const float* W_ih = (const float*)d_in[3];
  const float* W_hh = (const float*)d_in[4];
  const float* b_ih = (const float*)d_in[5];
  const float* b_hh = (const float*)d_in[6];
  const float* W_dec = (const float*)d_in[7];
  const float* b_dec = (const float*)d_in[8];
  float* out = (float*)d_out;

  dim3 grid(NBLK);  // 1024 blocks x 16 rows
  dim3 block(512);
  lstm_fused<<<grid, block, 0, stream>>>(x, W_enc, b_enc, W_ih, W_hh, b_ih, b_hh,
                                         W_dec, b_dec, out);
}

// Round 7
// 243.255 us; speedup vs baseline: 1.3425x; 1.0739x over previous
//
#include <hip/hip_runtime.h>

#define T_STEPS 60
#define HID 128
#define ROWS 16
#define NBLK (16384 / ROWS)  // 1024 blocks

typedef __attribute__((ext_vector_type(8))) short short8;
typedef __attribute__((ext_vector_type(4))) short short4v;
typedef __attribute__((ext_vector_type(4))) float f32x4;

#define K1 1.44269504088896340736f  // log2(e)

__device__ __forceinline__ unsigned short f2bf(float f) {
  unsigned u = __float_as_uint(f);
  return (unsigned short)((u + 0x7fffu + ((u >> 16) & 1u)) >> 16);
}
__device__ __forceinline__ float bf2f(unsigned short s) {
  return __uint_as_float(((unsigned)s) << 16);
}
__device__ __forceinline__ float sigm(float x) {
  return __builtin_amdgcn_rcpf(1.0f + __expf(-x));
}

// LDS map (bytes):
//   [0,4096):     h buffer 0 (16 rows x 128 units bf16, row r at r*256, swizzled)
//   [4096,8192):  h buffer 1
//   [8192,8704):  W_dec f32 copy
#define HB0 0
#define HB1 4096
#define WD_BASE 8192
#define LDS_BYTES 8704

__global__ __launch_bounds__(512, 4) void lstm_fused(
    const float* __restrict__ x, const float* __restrict__ W_enc,
    const float* __restrict__ b_enc, const float* __restrict__ W_ih,
    const float* __restrict__ W_hh, const float* __restrict__ b_ih,
    const float* __restrict__ b_hh, const float* __restrict__ W_dec,
    const float* __restrict__ b_dec, float* __restrict__ out) {
  __shared__ __align__(16) unsigned char lds[LDS_BYTES];

  const int tid = threadIdx.x;
  const int wav = tid >> 6;
  const int lane = tid & 63;
  const int l15 = lane & 15;
  const int l4 = lane >> 4;
  const int u = wav * 16 + l15;        // hidden unit owned by this lane
  const int row0 = blockIdx.x * ROWS;  // global batch row base

  // zero h buf0 (4096 B)
  for (int i = tid; i < 1024; i += 512) ((unsigned*)(lds + HB0))[i] = 0u;
  // copy W_dec into LDS
  if (tid < 128) ((float*)(lds + WD_BASE))[tid] = W_dec[tid];

  // ---- xp = enc @ W_ih^T + b_ih + b_hh, f32 IN REGISTERS, acc layout ----
  // (f16/LDS xp was the R3/R5 failure; must stay f32.)
  float xpv[4][4];
  {
    float xr0[4], xr1[4], xr2[4];
#pragma unroll
    for (int v = 0; v < 4; ++v) {
      int r = 4 * l4 + v;  // C-fragment row for this lane
      const float* xp_ = x + (size_t)(row0 + r) * 3;
      xr0[v] = xp_[0];
      xr1[v] = xp_[1];
      xr2[v] = xp_[2];
    }
#pragma unroll
    for (int gt = 0; gt < 4; ++gt) {
      float bias = b_ih[gt * 128 + u] + b_hh[gt * 128 + u];
#pragma unroll
      for (int v = 0; v < 4; ++v) xpv[gt][v] = bias;
    }
    // coalesced-ish W_ih: each thread streams its 4 rows as float4
    const f32x4* wr0 = (const f32x4*)(W_ih + (size_t)u * 64);
    const f32x4* wr1 = (const f32x4*)(W_ih + (size_t)(128 + u) * 64);
    const f32x4* wr2 = (const f32x4*)(W_ih + (size_t)(256 + u) * 64);
    const f32x4* wr3 = (const f32x4*)(W_ih + (size_t)(384 + u) * 64);
    for (int e4 = 0; e4 < 16; ++e4) {
      f32x4 w0 = wr0[e4], w1 = wr1[e4], w2 = wr2[e4], w3 = wr3[e4];
#pragma unroll
      for (int j = 0; j < 4; ++j) {
        int e = e4 * 4 + j;
        float we0 = W_enc[e * 3], we1 = W_enc[e * 3 + 1], we2 = W_enc[e * 3 + 2];
        float be = b_enc[e];
#pragma unroll
        for (int v = 0; v < 4; ++v) {
          float ev = fmaf(we0, xr0[v], fmaf(we1, xr1[v], fmaf(we2, xr2[v], be)));
          xpv[0][v] = fmaf(w0[j], ev, xpv[0][v]);
          xpv[1][v] = fmaf(w1[j], ev, xpv[1][v]);
          xpv[2][v] = fmaf(w2[j], ev, xpv[2][v]);
          xpv[3][v] = fmaf(w3[j], ev, xpv[3][v]);
        }
      }
    }
    // prescale into exp2 domain: y = -log2e * preact (i,f,o), -2log2e (g)
#pragma unroll
    for (int gt = 0; gt < 4; ++gt) {
      float s = (gt == 2) ? (-2.0f * K1) : (-K1);
#pragma unroll
      for (int v = 0; v < 4; ++v) xpv[gt][v] *= s;
    }
  }

  // ---- W_hh as register-resident bf16 B-fragments, prescaled into exp2 domain ----
  short8 bw[4][4];
#pragma unroll
  for (int gt = 0; gt < 4; ++gt) {
    float s = (gt == 2) ? (-2.0f * K1) : (-K1);
#pragma unroll
    for (int kt = 0; kt < 4; ++kt) {
      const float* p = W_hh + (size_t)(gt * 128 + u) * HID + kt * 32 + 8 * l4;
      short8 f;
#pragma unroll
      for (int j = 0; j < 8; ++j) f[j] = (short)f2bf(s * p[j]);
      bw[gt][kt] = f;
    }
  }

  // c held in scaled domain: ct = -2log2e * c  (so e^{-2c} = 2^ct)
  float ct[4];
#pragma unroll
  for (int v = 0; v < 4; ++v) ct[v] = 0.0f;

  // ---- precomputed LDS addresses (swizzle bits 4-6, consistent on rd/wr) ----
  const unsigned swzA =
      (((unsigned)(l15 & 7)) << 4) ^ (((unsigned)(l15 & 8)) << 2);
  unsigned rdA[4];
#pragma unroll
  for (int kt = 0; kt < 4; ++kt)
    rdA[kt] = ((unsigned)(l15 * 256 + l4 * 16 + kt * 64)) ^ swzA;
  unsigned wrA[4];
#pragma unroll
  for (int v = 0; v < 4; ++v) {
    unsigned rr = (unsigned)(4 * l4 + v);
    wrA[v] = (rr * 256 + (unsigned)u * 2) ^ ((rr & 7u) << 4) ^ ((rr & 8u) << 2);
  }
  // decode: half-wave handles one row; 32 lanes x 4 units each
  const int drow = wav * 2 + (l4 >> 1);
  const int idx = (l4 & 1) * 16 + l15;  // unit group: units idx*4 .. idx*4+3
  const unsigned dA = ((unsigned)(drow * 256 + idx * 8)) ^
                      (((unsigned)(drow & 7)) << 4) ^ (((unsigned)(drow & 8)) << 2);
  const int outIdx = (row0 + drow) * T_STEPS;
  const float bdec = b_dec[0];
  const float kneg = -2.0f * K1;  // k
  const float kpos = 2.0f * K1;   // -k

  __syncthreads();

#define STEP(RB, WB, tcur)                                                     \
  {                                                                            \
    f32x4 acc[4];                                                              \
    _Pragma("unroll") for (int gt = 0; gt < 4; ++gt) {                         \
      acc[gt][0] = xpv[gt][0];                                                 \
      acc[gt][1] = xpv[gt][1];                                                 \
      acc[gt][2] = xpv[gt][2];                                                 \
      acc[gt][3] = xpv[gt][3];                                                 \
    }                                                                          \
    _Pragma("unroll") for (int kt = 0; kt < 4; ++kt) {                         \
      short8 af = *(const short8*)(lds + (RB) + rdA[kt]);                      \
      _Pragma("unroll") for (int gt = 0; gt < 4; ++gt) acc[gt] =               \
          __builtin_amdgcn_mfma_f32_16x16x32_bf16(af, bw[gt][kt], acc[gt],     \
                                                  0, 0, 0);                    \
    }                                                                          \
    _Pragma("unroll") for (int v = 0; v < 4; ++v) {                            \
      float ea = __builtin_amdgcn_exp2f(acc[0][v]); /* e^{-i} */               \
      float ef = __builtin_amdgcn_exp2f(acc[1][v]); /* e^{-f} */               \
      float eg = __builtin_amdgcn_exp2f(acc[2][v]); /* e^{-2g} */              \
      float eo = __builtin_amdgcn_exp2f(acc[3][v]); /* e^{-o} */               \
      float A = 1.0f + ea, F = 1.0f + ef, G = 1.0f + eg, Bo = 1.0f + eo;       \
      float AG = A * G;                                                        \
      float r = __builtin_amdgcn_rcpf(F * AG);                                 \
      float t = fmaf(kpos, eg, kneg); /* k*(1-eg) */                           \
      float num = fmaf(ct[v], AG, t * F);                                      \
      float cn = num * r; /* new scaled c */                                   \
      ct[v] = cn;                                                              \
      float ec = __builtin_amdgcn_exp2f(cn); /* e^{-2c} */                     \
      float r2 = __builtin_amdgcn_rcpf(Bo * (1.0f + ec));                      \
      float h = (1.0f - ec) * r2; /* o * tanh(c) */                            \
      *(unsigned short*)(lds + (WB) + wrA[v]) = f2bf(h);                       \
    }                                                                          \
    __syncthreads();                                                           \
    {                                                                          \
      short4v hv = *(const short4v*)(lds + (WB) + dA);                         \
      f32x4 wd = *(const f32x4*)(lds + WD_BASE + idx * 16);                    \
      float dot = 0.f;                                                         \
      _Pragma("unroll") for (int i = 0; i < 4; ++i) dot =                      \
          fmaf(bf2f((unsigned short)hv[i]), wd[i], dot);                       \
      dot += __shfl_xor(dot, 1, 64);                                           \
      dot += __shfl_xor(dot, 2, 64);                                           \
      dot += __shfl_xor(dot, 4, 64);                                           \
      dot += __shfl_xor(dot, 8, 64);                                           \
      dot += __shfl_xor(dot, 16, 64);                                          \
      if ((lane & 31) == 0) out[outIdx + (tcur)] = sigm(dot + bdec);           \
    }                                                                          \
  }

  for (int t = 0; t < T_STEPS; t += 2) {
    STEP(HB0, HB1, t)
    STEP(HB1, HB0, t + 1)
  }
#undef STEP
}

extern "C" void kernel_launch(void* const* d_in, const int* in_sizes, int n_in,
                              void* d_out, int out_size, void* d_ws, size_t ws_size,
                              hipStream_t stream) {
  const float* x = (const float*)d_in[0];
  const float* W_enc = (const float*)d_in[1];
  const float* b_enc = (const float*)d_in[2];
  const float* W_ih = (const float*)d_in[3];
  const float* W_hh = (const float*)d_in[4];
  const float* b_ih = (const float*)d_in[5];
  const float* b_hh = (const float*)d_in[6];
  const float* W_dec = (const float*)d_in[7];
  const float* b_dec = (const float*)d_in[8];
  float* out = (float*)d_out;

  dim3 grid(NBLK);  // 1024 blocks x 16 rows
  dim3 block(512);
  lstm_fused<<<grid, block, 0, stream>>>(x, W_enc, b_enc, W_ih, W_hh, b_ih, b_hh,
                                         W_dec, b_dec, out);
}